// Round 2
// baseline (1457.512 us; speedup 1.0000x reference)
//
#include <hip/hip_runtime.h>
#include <hip/hip_bf16.h>

#define D_MODEL   1024
#define D_STATE   64
#define D_INNER   2048
#define NHEADS    32
#define CONV_DIM  2176
#define D_IN_PROJ 4256
#define NPAD      4352
#define BATCH     8
#define SEQ       1024
#define NROWS     8192

typedef __attribute__((ext_vector_type(8))) short bf16x8;
typedef __attribute__((ext_vector_type(4))) float f32x4;

__device__ __forceinline__ float bf2f(unsigned short u){
  unsigned v = ((unsigned)u) << 16;
  return __builtin_bit_cast(float, v);
}
__device__ __forceinline__ unsigned short f2bf(float f){
  __hip_bfloat16 h = __float2bfloat16(f);
  return __builtin_bit_cast(unsigned short, h);
}

// ---------------- convert x (fp32 -> bf16) ----------------
__global__ __launch_bounds__(256) void k_convert_x(const float* __restrict__ x,
                                                   unsigned short* __restrict__ xb){
  int i = blockIdx.x*256 + threadIdx.x;           // 2,097,152 float4s
  float4 v = ((const float4*)x)[i];
  ushort4 o;
  o.x = f2bf(v.x); o.y = f2bf(v.y); o.z = f2bf(v.z); o.w = f2bf(v.w);
  ((ushort4*)xb)[i] = o;
}

// ---------------- transpose W_in [K][N] -> bf16 [NPAD][K] (zero-pad rows) ----
__global__ __launch_bounds__(256) void k_transpose_win(const float* __restrict__ W_in,
                                                       unsigned short* __restrict__ wt){
  __shared__ float tile[32][33];
  int n0 = blockIdx.x * 32;     // 136 tiles -> 4352
  int k0 = blockIdx.y * 32;     // 32 tiles  -> 1024
  int tx = threadIdx.x & 31;
  int ty = threadIdx.x >> 5;    // 0..7
  #pragma unroll
  for (int i = 0; i < 4; ++i){
    int kk = ty + i*8;
    int n  = n0 + tx;
    tile[kk][tx] = (n < D_IN_PROJ) ? W_in[(size_t)(k0+kk)*D_IN_PROJ + n] : 0.f;
  }
  __syncthreads();
  #pragma unroll
  for (int i = 0; i < 4; ++i){
    int nn = ty + i*8;
    wt[(size_t)(n0+nn)*D_MODEL + k0 + tx] = f2bf(tile[tx][nn]);
  }
}

// ---------------- nwc[d] = norm_w[d] * sum_k W_out[d][k]*head_w[k] ----------
__global__ __launch_bounds__(256) void k_nwc(const float* __restrict__ W_out,
                                             const float* __restrict__ head_w,
                                             const float* __restrict__ norm_w,
                                             float* __restrict__ nwc){
  int d    = blockIdx.x*4 + (threadIdx.x >> 6);   // 512 blocks -> 2048 rows
  int lane = threadIdx.x & 63;
  const float* row = W_out + (size_t)d * D_MODEL;
  float s = 0.f;
  #pragma unroll
  for (int k = lane; k < D_MODEL; k += 64) s += row[k] * head_w[k];
  #pragma unroll
  for (int off = 32; off; off >>= 1) s += __shfl_down(s, off);
  if (lane == 0) nwc[d] = s * norm_w[d];
}

// ---------------- bf16 MFMA GEMM: C[M][N] = A[M][K] * BT[N][K]^T, bf16 out --
__global__ __launch_bounds__(256) void k_gemm_bf16_bt(const unsigned short* __restrict__ A,
                                                      const unsigned short* __restrict__ BT,
                                                      unsigned short* __restrict__ C,
                                                      int M, int N, int K){
  __shared__ unsigned short aT[128*64];
  __shared__ unsigned short bT[128*64];
  int nb   = N >> 7;
  int m0   = (blockIdx.x / nb) << 7;
  int n0   = (blockIdx.x % nb) << 7;
  int tid  = threadIdx.x;
  int wid  = tid >> 6, lane = tid & 63;
  int wr   = wid >> 1, wc = wid & 1;

  f32x4 acc[4][4];
  #pragma unroll
  for (int i = 0; i < 4; ++i)
    #pragma unroll
    for (int j = 0; j < 4; ++j)
      acc[i][j] = (f32x4){0.f, 0.f, 0.f, 0.f};

  int frow = lane & 15;            // m/n within 16x16 frag
  int fk   = (lane >> 4) << 3;     // k sub-block 0/8/16/24
  int srow = lane >> 3;            // staging: row within 8-row chunk
  int skk  = (lane & 7) << 3;      // staging: k offset (8 bf16 = 16B)

  for (int k0 = 0; k0 < K; k0 += 64){
    __syncthreads();
    #pragma unroll
    for (int it = 0; it < 4; ++it){
      int ch  = (wid << 2) | it;           // 16 chunks of 8 rows
      int row = (ch << 3) | srow;
      __builtin_amdgcn_global_load_lds(
        (const __attribute__((address_space(1))) void*)(A  + (size_t)(m0+row)*K + k0 + skk),
        (__attribute__((address_space(3))) void*)(aT + (ch << 9)), 16, 0, 0);
      __builtin_amdgcn_global_load_lds(
        (const __attribute__((address_space(1))) void*)(BT + (size_t)(n0+row)*K + k0 + skk),
        (__attribute__((address_space(3))) void*)(bT + (ch << 9)), 16, 0, 0);
    }
    __syncthreads();
    #pragma unroll
    for (int kk = 0; kk < 64; kk += 32){
      bf16x8 af[4], bfv[4];
      #pragma unroll
      for (int i = 0; i < 4; ++i)
        af[i]  = *(const bf16x8*)(aT + ((wr*64 + i*16 + frow) << 6) + kk + fk);
      #pragma unroll
      for (int j = 0; j < 4; ++j)
        bfv[j] = *(const bf16x8*)(bT + ((wc*64 + j*16 + frow) << 6) + kk + fk);
      #pragma unroll
      for (int i = 0; i < 4; ++i)
        #pragma unroll
        for (int j = 0; j < 4; ++j)
          acc[i][j] = __builtin_amdgcn_mfma_f32_16x16x32_bf16(af[i], bfv[j], acc[i][j], 0, 0, 0);
    }
  }

  int crow = (lane >> 4) << 2;
  int ccol = lane & 15;
  #pragma unroll
  for (int i = 0; i < 4; ++i)
    #pragma unroll
    for (int j = 0; j < 4; ++j){
      size_t base = (size_t)(m0 + wr*64 + i*16 + crow) * N + (n0 + wc*64 + j*16 + ccol);
      #pragma unroll
      for (int r = 0; r < 4; ++r)
        C[base + (size_t)r * N] = f2bf(acc[i][j][r]);
    }
}

// ---------------- dt = softplus(raw + bias), dA = exp(dt * -exp(A_log)) ----
__global__ __launch_bounds__(256) void k_dtda(const unsigned short* __restrict__ zx,
                                              const float* __restrict__ dt_bias,
                                              const float* __restrict__ A_log,
                                              float* __restrict__ dtb,
                                              float* __restrict__ dab){
  int i = blockIdx.x*256 + threadIdx.x;           // 262,144
  int r = i >> 5, h = i & 31;
  float raw = bf2f(zx[(size_t)r*NPAD + D_INNER + CONV_DIM + h]) + dt_bias[h];
  float dt  = (raw > 20.f) ? raw : log1pf(expf(raw));
  float A   = -expf(A_log[h]);
  dtb[i] = dt;
  dab[i] = expf(dt * A);
}

// ---------------- causal conv1d (4 taps) + SiLU -> bf16 ---------------------
__global__ __launch_bounds__(256) void k_conv(const unsigned short* __restrict__ zx,
                                              const float* __restrict__ conv_w,
                                              const float* __restrict__ conv_b,
                                              unsigned short* __restrict__ xbc){
  int c = blockIdx.x*256 + threadIdx.x;
  if (c >= CONV_DIM) return;
  int r = blockIdx.y;
  int l = r & (SEQ - 1);
  float v = conv_b[c];
  #pragma unroll
  for (int k = 0; k < 4; ++k){
    int dl = l + k - 3;
    if (dl >= 0)
      v += bf2f(zx[(size_t)(r + k - 3)*NPAD + D_INNER + c]) * conv_w[k*CONV_DIM + c];
  }
  float s = v / (1.f + expf(-v));
  xbc[(size_t)r*CONV_DIM + c] = f2bf(s);
}

// ---------------- sequential SSM scan: 1 wave per (b,h), lane = p -----------
__global__ __launch_bounds__(64) void k_scan(const unsigned short* __restrict__ xbc,
                                             const float* __restrict__ dtb,
                                             const float* __restrict__ dab,
                                             const float* __restrict__ Dskip,
                                             unsigned short* __restrict__ y){
  int bh = blockIdx.x;
  int b  = bh >> 5, h = bh & 31;
  int p  = threadIdx.x;
  __shared__ __align__(16) float Bs[2][64];
  __shared__ __align__(16) float Cs[2][64];

  float hst[64];
  #pragma unroll
  for (int i = 0; i < 64; ++i) hst[i] = 0.f;
  float dskip_h = Dskip[h];

  size_t rbase = (size_t)b * SEQ * CONV_DIM;
  // preload t = 0
  unsigned short xv = xbc[rbase + h*64 + p];
  unsigned short bv = xbc[rbase + D_INNER + p];
  unsigned short cv = xbc[rbase + D_INNER + D_STATE + p];
  float dtv = dtb[(b*SEQ + 0)*32 + h];
  float dAv = dab[(b*SEQ + 0)*32 + h];

  for (int t = 0; t < SEQ; ++t){
    int buf = t & 1;
    Bs[buf][p] = bf2f(bv);
    Cs[buf][p] = bf2f(cv);
    float xf  = bf2f(xv);
    float dtc = dtv, dac = dAv;
    if (t + 1 < SEQ){
      size_t ro = rbase + (size_t)(t+1)*CONV_DIM;
      xv  = xbc[ro + h*64 + p];
      bv  = xbc[ro + D_INNER + p];
      cv  = xbc[ro + D_INNER + D_STATE + p];
      dtv = dtb[(b*SEQ + t+1)*32 + h];
      dAv = dab[(b*SEQ + t+1)*32 + h];
    }
    __syncthreads();
    float kk = dtc * xf;
    float4 ys = {0.f, 0.f, 0.f, 0.f};
    #pragma unroll
    for (int s4 = 0; s4 < 16; ++s4){
      float4 b4 = *(const float4*)&Bs[buf][s4 << 2];
      float4 c4 = *(const float4*)&Cs[buf][s4 << 2];
      float* hp = &hst[s4 << 2];
      hp[0] = fmaf(hp[0], dac, kk*b4.x); ys.x = fmaf(hp[0], c4.x, ys.x);
      hp[1] = fmaf(hp[1], dac, kk*b4.y); ys.y = fmaf(hp[1], c4.y, ys.y);
      hp[2] = fmaf(hp[2], dac, kk*b4.z); ys.z = fmaf(hp[2], c4.z, ys.z);
      hp[3] = fmaf(hp[3], dac, kk*b4.w); ys.w = fmaf(hp[3], c4.w, ys.w);
    }
    float ysum = (ys.x + ys.y) + (ys.z + ys.w);
    y[(size_t)(b*SEQ + t)*D_INNER + h*64 + p] = f2bf(ysum + dskip_h * xf);
    __syncthreads();
  }
}

// ---------------- fused gate + RMS + (norm_w*W_out@head_w) dot --------------
__global__ __launch_bounds__(256) void k_epilogue(const unsigned short* __restrict__ y,
                                                  const unsigned short* __restrict__ zx,
                                                  const float* __restrict__ nwc,
                                                  const float* __restrict__ head_b,
                                                  float* __restrict__ out){
  int r   = blockIdx.x;
  int tid = threadIdx.x;
  bf16x8 y8 = *(const bf16x8*)(y  + (size_t)r*D_INNER + tid*8);
  bf16x8 z8 = *(const bf16x8*)(zx + (size_t)r*NPAD   + tid*8);
  float4 w0 = ((const float4*)nwc)[tid*2];
  float4 w1 = ((const float4*)nwc)[tid*2 + 1];
  float wv[8] = {w0.x, w0.y, w0.z, w0.w, w1.x, w1.y, w1.z, w1.w};
  float s2 = 0.f, sd = 0.f;
  #pragma unroll
  for (int k = 0; k < 8; ++k){
    float yf = bf2f((unsigned short)y8[k]);
    float zf = bf2f((unsigned short)z8[k]);
    float g  = yf * (zf / (1.f + expf(-zf)));
    s2 += g*g; sd += g*wv[k];
  }
  #pragma unroll
  for (int off = 32; off; off >>= 1){
    s2 += __shfl_down(s2, off);
    sd += __shfl_down(sd, off);
  }
  __shared__ float r2[4], rd[4];
  if ((tid & 63) == 0){ r2[tid >> 6] = s2; rd[tid >> 6] = sd; }
  __syncthreads();
  if (tid == 0){
    float t2 = r2[0] + r2[1] + r2[2] + r2[3];
    float td = rd[0] + rd[1] + rd[2] + rd[3];
    out[r] = rsqrtf(t2 * (1.f/2048.f) + 1e-5f) * td + head_b[0];
  }
}

extern "C" void kernel_launch(void* const* d_in, const int* in_sizes, int n_in,
                              void* d_out, int out_size, void* d_ws, size_t ws_size,
                              hipStream_t stream){
  const float* x       = (const float*)d_in[0];
  const float* W_in    = (const float*)d_in[1];
  const float* conv_w  = (const float*)d_in[2];
  const float* conv_b  = (const float*)d_in[3];
  const float* dt_bias = (const float*)d_in[4];
  const float* A_log   = (const float*)d_in[5];
  const float* Dskip   = (const float*)d_in[6];
  const float* norm_w  = (const float*)d_in[7];
  const float* W_out   = (const float*)d_in[8];
  const float* head_w  = (const float*)d_in[9];
  const float* head_b  = (const float*)d_in[10];
  float* out = (float*)d_out;

  // ws layout (total 168,304,640 B ~= 160.5 MiB)
  char* ws = (char*)d_ws;
  unsigned short* xb   = (unsigned short*)(ws + 0);            // 16,777,216
  unsigned short* wt   = (unsigned short*)(ws + 16777216);     //  8,912,896
  unsigned short* zx16 = (unsigned short*)(ws + 25690112);     // 71,303,168
  unsigned short* xbc  = (unsigned short*)(ws + 96993280);     // 35,651,584
  float*          dtb  = (float*)         (ws + 132644864);    //  1,048,576
  float*          dab  = (float*)         (ws + 133693440);    //  1,048,576
  float*          nwc  = (float*)         (ws + 134742016);    //      8,192
  unsigned short* yb   = (unsigned short*)(ws + 134750208);    // 33,554,432

  k_convert_x<<<8192, 256, 0, stream>>>(x, xb);
  k_transpose_win<<<dim3(136, 32), 256, 0, stream>>>(W_in, wt);
  k_nwc<<<512, 256, 0, stream>>>(W_out, head_w, norm_w, nwc);
  k_gemm_bf16_bt<<<(NROWS/128)*(NPAD/128), 256, 0, stream>>>(xb, wt, zx16, NROWS, NPAD, D_MODEL);
  k_dtda<<<1024, 256, 0, stream>>>(zx16, dt_bias, A_log, dtb, dab);
  k_conv<<<dim3(9, NROWS), 256, 0, stream>>>(zx16, conv_w, conv_b, xbc);
  k_scan<<<256, 64, 0, stream>>>(xbc, dtb, dab, Dskip, yb);
  k_epilogue<<<NROWS, 256, 0, stream>>>(yb, zx16, nwc, head_b, out);
}

// Round 3
// 528.879 us; speedup vs baseline: 2.7559x; 2.7559x over previous
//
#include <hip/hip_runtime.h>
#include <hip/hip_bf16.h>

#define D_MODEL   1024
#define D_STATE   64
#define D_INNER   2048
#define NHEADS    32
#define CONV_DIM  2176
#define D_IN_PROJ 4256
#define NPAD      4352
#define BATCH     8
#define SEQ       1024
#define NROWS     8192
#define NCHUNK    8
#define CLEN      128

typedef __attribute__((ext_vector_type(8))) short bf16x8;
typedef __attribute__((ext_vector_type(4))) float f32x4;

__device__ __forceinline__ float bf2f(unsigned short u){
  unsigned v = ((unsigned)u) << 16;
  return __builtin_bit_cast(float, v);
}
__device__ __forceinline__ unsigned short f2bf(float f){
  __hip_bfloat16 h = __float2bfloat16(f);
  return __builtin_bit_cast(unsigned short, h);
}

// ---------------- convert x (fp32 -> bf16) ----------------
__global__ __launch_bounds__(256) void k_convert_x(const float* __restrict__ x,
                                                   unsigned short* __restrict__ xb){
  int i = blockIdx.x*256 + threadIdx.x;
  float4 v = ((const float4*)x)[i];
  ushort4 o;
  o.x = f2bf(v.x); o.y = f2bf(v.y); o.z = f2bf(v.z); o.w = f2bf(v.w);
  ((ushort4*)xb)[i] = o;
}

// ---------------- transpose W_in [K][N] -> bf16 [NPAD][K] -------------------
__global__ __launch_bounds__(256) void k_transpose_win(const float* __restrict__ W_in,
                                                       unsigned short* __restrict__ wt){
  __shared__ float tile[32][33];
  int n0 = blockIdx.x * 32;
  int k0 = blockIdx.y * 32;
  int tx = threadIdx.x & 31;
  int ty = threadIdx.x >> 5;
  #pragma unroll
  for (int i = 0; i < 4; ++i){
    int kk = ty + i*8;
    int n  = n0 + tx;
    tile[kk][tx] = (n < D_IN_PROJ) ? W_in[(size_t)(k0+kk)*D_IN_PROJ + n] : 0.f;
  }
  __syncthreads();
  #pragma unroll
  for (int i = 0; i < 4; ++i){
    int nn = ty + i*8;
    wt[(size_t)(n0+nn)*D_MODEL + k0 + tx] = f2bf(tile[tx][nn]);
  }
}

// ---------------- nwc[d] = norm_w[d] * sum_k W_out[d][k]*head_w[k] ----------
__global__ __launch_bounds__(256) void k_nwc(const float* __restrict__ W_out,
                                             const float* __restrict__ head_w,
                                             const float* __restrict__ norm_w,
                                             float* __restrict__ nwc){
  int d    = blockIdx.x*4 + (threadIdx.x >> 6);
  int lane = threadIdx.x & 63;
  const float* row = W_out + (size_t)d * D_MODEL;
  float s = 0.f;
  #pragma unroll
  for (int k = lane; k < D_MODEL; k += 64) s += row[k] * head_w[k];
  #pragma unroll
  for (int off = 32; off; off >>= 1) s += __shfl_down(s, off);
  if (lane == 0) nwc[d] = s * norm_w[d];
}

// ---------------- bf16 MFMA GEMM: C[M][N] = A[M][K] * BT[N][K]^T, bf16 out --
__global__ __launch_bounds__(256) void k_gemm_bf16_bt(const unsigned short* __restrict__ A,
                                                      const unsigned short* __restrict__ BT,
                                                      unsigned short* __restrict__ C,
                                                      int M, int N, int K){
  __shared__ unsigned short aT[128*64];
  __shared__ unsigned short bT[128*64];
  int nb   = N >> 7;
  int m0   = (blockIdx.x / nb) << 7;
  int n0   = (blockIdx.x % nb) << 7;
  int tid  = threadIdx.x;
  int wid  = tid >> 6, lane = tid & 63;
  int wr   = wid >> 1, wc = wid & 1;

  f32x4 acc[4][4];
  #pragma unroll
  for (int i = 0; i < 4; ++i)
    #pragma unroll
    for (int j = 0; j < 4; ++j)
      acc[i][j] = (f32x4){0.f, 0.f, 0.f, 0.f};

  int frow = lane & 15;
  int fk   = (lane >> 4) << 3;
  int srow = lane >> 3;
  int skk  = (lane & 7) << 3;

  for (int k0 = 0; k0 < K; k0 += 64){
    __syncthreads();
    #pragma unroll
    for (int it = 0; it < 4; ++it){
      int ch  = (wid << 2) | it;
      int row = (ch << 3) | srow;
      __builtin_amdgcn_global_load_lds(
        (const __attribute__((address_space(1))) void*)(A  + (size_t)(m0+row)*K + k0 + skk),
        (__attribute__((address_space(3))) void*)(aT + (ch << 9)), 16, 0, 0);
      __builtin_amdgcn_global_load_lds(
        (const __attribute__((address_space(1))) void*)(BT + (size_t)(n0+row)*K + k0 + skk),
        (__attribute__((address_space(3))) void*)(bT + (ch << 9)), 16, 0, 0);
    }
    __syncthreads();
    #pragma unroll
    for (int kk = 0; kk < 64; kk += 32){
      bf16x8 af[4], bfv[4];
      #pragma unroll
      for (int i = 0; i < 4; ++i)
        af[i]  = *(const bf16x8*)(aT + ((wr*64 + i*16 + frow) << 6) + kk + fk);
      #pragma unroll
      for (int j = 0; j < 4; ++j)
        bfv[j] = *(const bf16x8*)(bT + ((wc*64 + j*16 + frow) << 6) + kk + fk);
      #pragma unroll
      for (int i = 0; i < 4; ++i)
        #pragma unroll
        for (int j = 0; j < 4; ++j)
          acc[i][j] = __builtin_amdgcn_mfma_f32_16x16x32_bf16(af[i], bfv[j], acc[i][j], 0, 0, 0);
    }
  }

  int crow = (lane >> 4) << 2;
  int ccol = lane & 15;
  #pragma unroll
  for (int i = 0; i < 4; ++i)
    #pragma unroll
    for (int j = 0; j < 4; ++j){
      size_t base = (size_t)(m0 + wr*64 + i*16 + crow) * N + (n0 + wc*64 + j*16 + ccol);
      #pragma unroll
      for (int r = 0; r < 4; ++r)
        C[base + (size_t)r * N] = f2bf(acc[i][j][r]);
    }
}

// ---------------- dt = softplus(raw + bias), dA = exp(dt * -exp(A_log)) ----
__global__ __launch_bounds__(256) void k_dtda(const unsigned short* __restrict__ zx,
                                              const float* __restrict__ dt_bias,
                                              const float* __restrict__ A_log,
                                              float* __restrict__ dtb,
                                              float* __restrict__ dab){
  int i = blockIdx.x*256 + threadIdx.x;
  int r = i >> 5, h = i & 31;
  float raw = bf2f(zx[(size_t)r*NPAD + D_INNER + CONV_DIM + h]) + dt_bias[h];
  float dt  = (raw > 20.f) ? raw : log1pf(expf(raw));
  float A   = -expf(A_log[h]);
  dtb[i] = dt;
  dab[i] = expf(dt * A);
}

// ---------------- causal conv1d (4 taps) + SiLU -> bf16 ---------------------
__global__ __launch_bounds__(256) void k_conv(const unsigned short* __restrict__ zx,
                                              const float* __restrict__ conv_w,
                                              const float* __restrict__ conv_b,
                                              unsigned short* __restrict__ xbc){
  int c = blockIdx.x*256 + threadIdx.x;
  if (c >= CONV_DIM) return;
  int r = blockIdx.y;
  int l = r & (SEQ - 1);
  float v = conv_b[c];
  #pragma unroll
  for (int k = 0; k < 4; ++k){
    int dl = l + k - 3;
    if (dl >= 0)
      v += bf2f(zx[(size_t)(r + k - 3)*NPAD + D_INNER + c]) * conv_w[k*CONV_DIM + c];
  }
  float s = v / (1.f + expf(-v));
  xbc[(size_t)r*CONV_DIM + c] = f2bf(s);
}

// ---------------- scan pass 1: per-chunk local h_end + cumA -----------------
// grid: 2048 = bh*8 + c; block: 64. State in regs (static indices only).
__global__ __launch_bounds__(64) void k_scan1(const unsigned short* __restrict__ xbc,
                                              const float* __restrict__ dtb,
                                              const float* __restrict__ dab,
                                              unsigned short* __restrict__ hend,
                                              float* __restrict__ cumA){
  int id = blockIdx.x;
  int bh = id >> 3, c = id & 7;
  int b  = bh >> 5, h = bh & 31;
  int p  = threadIdx.x;
  __shared__ __align__(16) float Bs[2][64];

  float4 h4[16];
  #pragma unroll
  for (int i = 0; i < 16; ++i) h4[i] = make_float4(0.f, 0.f, 0.f, 0.f);
  float ca = 1.f;

  size_t rbase = (size_t)b * SEQ * CONV_DIM;
  int t0 = c << 7;
  size_t r0 = rbase + (size_t)t0 * CONV_DIM;
  unsigned short xv = xbc[r0 + h*64 + p];
  unsigned short bv = xbc[r0 + D_INNER + p];
  float dtv = dtb[(b*SEQ + t0)*32 + h];
  float dAv = dab[(b*SEQ + t0)*32 + h];

  for (int tt = 0; tt < CLEN; ++tt){
    int buf = tt & 1;
    Bs[buf][p] = bf2f(bv);
    float xf = bf2f(xv), dtc = dtv, dac = dAv;
    if (tt + 1 < CLEN){
      size_t ro = rbase + (size_t)(t0 + tt + 1) * CONV_DIM;
      xv  = xbc[ro + h*64 + p];
      bv  = xbc[ro + D_INNER + p];
      dtv = dtb[(b*SEQ + t0 + tt + 1)*32 + h];
      dAv = dab[(b*SEQ + t0 + tt + 1)*32 + h];
    }
    __syncthreads();
    float kk = dtc * xf;
    ca *= dac;
    #pragma unroll
    for (int s4 = 0; s4 < 16; ++s4){
      float4 b4 = *(const float4*)&Bs[buf][s4 << 2];
      h4[s4].x = fmaf(h4[s4].x, dac, kk*b4.x);
      h4[s4].y = fmaf(h4[s4].y, dac, kk*b4.y);
      h4[s4].z = fmaf(h4[s4].z, dac, kk*b4.z);
      h4[s4].w = fmaf(h4[s4].w, dac, kk*b4.w);
    }
  }
  // store h_end as [id][s][p] (each 2B store coalesced across lanes)
  size_t hb = ((size_t)id << 12) + p;
  #pragma unroll
  for (int s4 = 0; s4 < 16; ++s4){
    hend[hb + (size_t)(s4*4+0)*64] = f2bf(h4[s4].x);
    hend[hb + (size_t)(s4*4+1)*64] = f2bf(h4[s4].y);
    hend[hb + (size_t)(s4*4+2)*64] = f2bf(h4[s4].z);
    hend[hb + (size_t)(s4*4+3)*64] = f2bf(h4[s4].w);
  }
  if (p == 0) cumA[id] = ca;
}

// ---------------- combine: carry chunk states (in-place hend -> h_init) -----
// grid: 256 (bh); block: 256. Thread owns 16 contiguous elems of the 4096.
__global__ __launch_bounds__(256) void k_comb(unsigned short* __restrict__ hh,
                                              const float* __restrict__ cumA){
  int bh = blockIdx.x, tid = threadIdx.x;
  float carry[16];
  #pragma unroll
  for (int i = 0; i < 16; ++i) carry[i] = 0.f;
  #pragma unroll
  for (int c = 0; c < NCHUNK; ++c){
    size_t base = (((size_t)bh*NCHUNK + c) << 12) + tid*16;
    bf16x8 a0 = *(const bf16x8*)(hh + base);
    bf16x8 a1 = *(const bf16x8*)(hh + base + 8);
    float ca = cumA[bh*NCHUNK + c];
    float tmp[16];
    #pragma unroll
    for (int i = 0; i < 8; ++i){
      tmp[i]   = bf2f((unsigned short)a0[i]);
      tmp[8+i] = bf2f((unsigned short)a1[i]);
    }
    bf16x8 w0, w1;
    #pragma unroll
    for (int i = 0; i < 8; ++i){
      w0[i] = (short)f2bf(carry[i]);
      w1[i] = (short)f2bf(carry[8+i]);
    }
    *(bf16x8*)(hh + base)     = w0;
    *(bf16x8*)(hh + base + 8) = w1;
    #pragma unroll
    for (int i = 0; i < 16; ++i) carry[i] = tmp[i] + ca*carry[i];
  }
}

// ---------------- scan pass 2: real scan from h_init, emit y ----------------
__global__ __launch_bounds__(64) void k_scan2(const unsigned short* __restrict__ xbc,
                                              const float* __restrict__ dtb,
                                              const float* __restrict__ dab,
                                              const float* __restrict__ Dskip,
                                              const unsigned short* __restrict__ hinit,
                                              unsigned short* __restrict__ y){
  int id = blockIdx.x;
  int bh = id >> 3, c = id & 7;
  int b  = bh >> 5, h = bh & 31;
  int p  = threadIdx.x;
  __shared__ __align__(16) float Bs[2][64];
  __shared__ __align__(16) float Cs[2][64];

  float4 h4[16];
  size_t ib = ((size_t)id << 12) + p;
  #pragma unroll
  for (int s4 = 0; s4 < 16; ++s4){
    h4[s4].x = bf2f(hinit[ib + (size_t)(s4*4+0)*64]);
    h4[s4].y = bf2f(hinit[ib + (size_t)(s4*4+1)*64]);
    h4[s4].z = bf2f(hinit[ib + (size_t)(s4*4+2)*64]);
    h4[s4].w = bf2f(hinit[ib + (size_t)(s4*4+3)*64]);
  }
  float dskip_h = Dskip[h];

  size_t rbase = (size_t)b * SEQ * CONV_DIM;
  int t0 = c << 7;
  size_t r0 = rbase + (size_t)t0 * CONV_DIM;
  unsigned short xv = xbc[r0 + h*64 + p];
  unsigned short bv = xbc[r0 + D_INNER + p];
  unsigned short cv = xbc[r0 + D_INNER + D_STATE + p];
  float dtv = dtb[(b*SEQ + t0)*32 + h];
  float dAv = dab[(b*SEQ + t0)*32 + h];

  for (int tt = 0; tt < CLEN; ++tt){
    int t   = t0 + tt;
    int buf = tt & 1;
    Bs[buf][p] = bf2f(bv);
    Cs[buf][p] = bf2f(cv);
    float xf = bf2f(xv), dtc = dtv, dac = dAv;
    if (tt + 1 < CLEN){
      size_t ro = rbase + (size_t)(t + 1) * CONV_DIM;
      xv  = xbc[ro + h*64 + p];
      bv  = xbc[ro + D_INNER + p];
      cv  = xbc[ro + D_INNER + D_STATE + p];
      dtv = dtb[(b*SEQ + t + 1)*32 + h];
      dAv = dab[(b*SEQ + t + 1)*32 + h];
    }
    __syncthreads();
    float kk = dtc * xf;
    float ysx = 0.f, ysy = 0.f, ysz = 0.f, ysw = 0.f;
    #pragma unroll
    for (int s4 = 0; s4 < 16; ++s4){
      float4 b4 = *(const float4*)&Bs[buf][s4 << 2];
      float4 c4 = *(const float4*)&Cs[buf][s4 << 2];
      h4[s4].x = fmaf(h4[s4].x, dac, kk*b4.x); ysx = fmaf(h4[s4].x, c4.x, ysx);
      h4[s4].y = fmaf(h4[s4].y, dac, kk*b4.y); ysy = fmaf(h4[s4].y, c4.y, ysy);
      h4[s4].z = fmaf(h4[s4].z, dac, kk*b4.z); ysz = fmaf(h4[s4].z, c4.z, ysz);
      h4[s4].w = fmaf(h4[s4].w, dac, kk*b4.w); ysw = fmaf(h4[s4].w, c4.w, ysw);
    }
    float ysum = (ysx + ysy) + (ysz + ysw);
    y[(size_t)(b*SEQ + t)*D_INNER + h*64 + p] = f2bf(ysum + dskip_h * xf);
  }
}

// ---------------- fused gate + RMS + (norm_w*W_out@head_w) dot --------------
__global__ __launch_bounds__(256) void k_epilogue(const unsigned short* __restrict__ y,
                                                  const unsigned short* __restrict__ zx,
                                                  const float* __restrict__ nwc,
                                                  const float* __restrict__ head_b,
                                                  float* __restrict__ out){
  int r   = blockIdx.x;
  int tid = threadIdx.x;
  bf16x8 y8 = *(const bf16x8*)(y  + (size_t)r*D_INNER + tid*8);
  bf16x8 z8 = *(const bf16x8*)(zx + (size_t)r*NPAD   + tid*8);
  float4 w0 = ((const float4*)nwc)[tid*2];
  float4 w1 = ((const float4*)nwc)[tid*2 + 1];
  float wv[8] = {w0.x, w0.y, w0.z, w0.w, w1.x, w1.y, w1.z, w1.w};
  float s2 = 0.f, sd = 0.f;
  #pragma unroll
  for (int k = 0; k < 8; ++k){
    float yf = bf2f((unsigned short)y8[k]);
    float zf = bf2f((unsigned short)z8[k]);
    float g  = yf * (zf / (1.f + expf(-zf)));
    s2 += g*g; sd += g*wv[k];
  }
  #pragma unroll
  for (int off = 32; off; off >>= 1){
    s2 += __shfl_down(s2, off);
    sd += __shfl_down(sd, off);
  }
  __shared__ float r2[4], rd[4];
  if ((tid & 63) == 0){ r2[tid >> 6] = s2; rd[tid >> 6] = sd; }
  __syncthreads();
  if (tid == 0){
    float t2 = r2[0] + r2[1] + r2[2] + r2[3];
    float td = rd[0] + rd[1] + rd[2] + rd[3];
    out[r] = rsqrtf(t2 * (1.f/2048.f) + 1e-5f) * td + head_b[0];
  }
}

extern "C" void kernel_launch(void* const* d_in, const int* in_sizes, int n_in,
                              void* d_out, int out_size, void* d_ws, size_t ws_size,
                              hipStream_t stream){
  const float* x       = (const float*)d_in[0];
  const float* W_in    = (const float*)d_in[1];
  const float* conv_w  = (const float*)d_in[2];
  const float* conv_b  = (const float*)d_in[3];
  const float* dt_bias = (const float*)d_in[4];
  const float* A_log   = (const float*)d_in[5];
  const float* Dskip   = (const float*)d_in[6];
  const float* norm_w  = (const float*)d_in[7];
  const float* W_out   = (const float*)d_in[8];
  const float* head_w  = (const float*)d_in[9];
  const float* head_b  = (const float*)d_in[10];
  float* out = (float*)d_out;

  // ws layout (peak 168,304,640 B)
  char* ws = (char*)d_ws;
  unsigned short* xb   = (unsigned short*)(ws + 0);            // 16,777,216 (reused as hend/hinit after gemm)
  unsigned short* wt   = (unsigned short*)(ws + 16777216);     //  8,912,896 (reused as cumA after gemm)
  unsigned short* zx16 = (unsigned short*)(ws + 25690112);     // 71,303,168
  unsigned short* xbc  = (unsigned short*)(ws + 96993280);     // 35,651,584
  float*          dtb  = (float*)         (ws + 132644864);    //  1,048,576
  float*          dab  = (float*)         (ws + 133693440);    //  1,048,576
  float*          nwc  = (float*)         (ws + 134742016);    //      8,192
  unsigned short* yb   = (unsigned short*)(ws + 134750208);    // 33,554,432

  unsigned short* hbuf = xb;                    // 256*8*4096*2B = 16,777,216 exactly
  float*          cumA = (float*)wt;            // 2048*4B

  k_convert_x<<<8192, 256, 0, stream>>>(x, xb);
  k_transpose_win<<<dim3(136, 32), 256, 0, stream>>>(W_in, wt);
  k_nwc<<<512, 256, 0, stream>>>(W_out, head_w, norm_w, nwc);
  k_gemm_bf16_bt<<<(NROWS/128)*(NPAD/128), 256, 0, stream>>>(xb, wt, zx16, NROWS, NPAD, D_MODEL);
  k_dtda<<<1024, 256, 0, stream>>>(zx16, dt_bias, A_log, dtb, dab);
  k_conv<<<dim3(9, NROWS), 256, 0, stream>>>(zx16, conv_w, conv_b, xbc);
  k_scan1<<<256*NCHUNK, 64, 0, stream>>>(xbc, dtb, dab, hbuf, cumA);
  k_comb<<<256, 256, 0, stream>>>(hbuf, cumA);
  k_scan2<<<256*NCHUNK, 64, 0, stream>>>(xbc, dtb, dab, Dskip, hbuf, yb);
  k_epilogue<<<NROWS, 256, 0, stream>>>(yb, zx16, nwc, head_b, out);
}

// Round 4
// 515.264 us; speedup vs baseline: 2.8287x; 1.0264x over previous
//
#include <hip/hip_runtime.h>
#include <hip/hip_bf16.h>

#define D_MODEL   1024
#define D_STATE   64
#define D_INNER   2048
#define NHEADS    32
#define CONV_DIM  2176
#define D_IN_PROJ 4256
#define NPAD      4352
#define BATCH     8
#define SEQ       1024
#define NROWS     8192
#define NCHUNK    8
#define CLEN      128

typedef __attribute__((ext_vector_type(8))) short bf16x8;
typedef __attribute__((ext_vector_type(4))) float f32x4;

__device__ __forceinline__ float bf2f(unsigned short u){
  unsigned v = ((unsigned)u) << 16;
  return __builtin_bit_cast(float, v);
}
__device__ __forceinline__ unsigned short f2bf(float f){
  __hip_bfloat16 h = __float2bfloat16(f);
  return __builtin_bit_cast(unsigned short, h);
}

#define HLIST(F) F(0) F(1) F(2) F(3) F(4) F(5) F(6) F(7) F(8) F(9) F(10) F(11) F(12) F(13) F(14) F(15)

// ---------------- convert x (fp32 -> bf16) ----------------
__global__ __launch_bounds__(256) void k_convert_x(const float* __restrict__ x,
                                                   unsigned short* __restrict__ xb){
  int i = blockIdx.x*256 + threadIdx.x;
  float4 v = ((const float4*)x)[i];
  ushort4 o;
  o.x = f2bf(v.x); o.y = f2bf(v.y); o.z = f2bf(v.z); o.w = f2bf(v.w);
  ((ushort4*)xb)[i] = o;
}

// ---------------- transpose W_in [K][N] -> bf16 [NPAD][K] -------------------
__global__ __launch_bounds__(256) void k_transpose_win(const float* __restrict__ W_in,
                                                       unsigned short* __restrict__ wt){
  __shared__ float tile[32][33];
  int n0 = blockIdx.x * 32;
  int k0 = blockIdx.y * 32;
  int tx = threadIdx.x & 31;
  int ty = threadIdx.x >> 5;
  #pragma unroll
  for (int i = 0; i < 4; ++i){
    int kk = ty + i*8;
    int n  = n0 + tx;
    tile[kk][tx] = (n < D_IN_PROJ) ? W_in[(size_t)(k0+kk)*D_IN_PROJ + n] : 0.f;
  }
  __syncthreads();
  #pragma unroll
  for (int i = 0; i < 4; ++i){
    int nn = ty + i*8;
    wt[(size_t)(n0+nn)*D_MODEL + k0 + tx] = f2bf(tile[tx][nn]);
  }
}

// ---------------- nwc[d] = norm_w[d] * sum_k W_out[d][k]*head_w[k] ----------
__global__ __launch_bounds__(256) void k_nwc(const float* __restrict__ W_out,
                                             const float* __restrict__ head_w,
                                             const float* __restrict__ norm_w,
                                             float* __restrict__ nwc){
  int d    = blockIdx.x*4 + (threadIdx.x >> 6);
  int lane = threadIdx.x & 63;
  const float* row = W_out + (size_t)d * D_MODEL;
  float s = 0.f;
  #pragma unroll
  for (int k = lane; k < D_MODEL; k += 64) s += row[k] * head_w[k];
  #pragma unroll
  for (int off = 32; off; off >>= 1) s += __shfl_down(s, off);
  if (lane == 0) nwc[d] = s * norm_w[d];
}

// ---------------- bf16 MFMA GEMM: C[M][N] = A[M][K] * BT[N][K]^T, bf16 out --
__global__ __launch_bounds__(256) void k_gemm_bf16_bt(const unsigned short* __restrict__ A,
                                                      const unsigned short* __restrict__ BT,
                                                      unsigned short* __restrict__ C,
                                                      int M, int N, int K){
  __shared__ unsigned short aT[128*64];
  __shared__ unsigned short bT[128*64];
  int nb   = N >> 7;
  int m0   = (blockIdx.x / nb) << 7;
  int n0   = (blockIdx.x % nb) << 7;
  int tid  = threadIdx.x;
  int wid  = tid >> 6, lane = tid & 63;
  int wr   = wid >> 1, wc = wid & 1;

  f32x4 acc[4][4];
  #pragma unroll
  for (int i = 0; i < 4; ++i)
    #pragma unroll
    for (int j = 0; j < 4; ++j)
      acc[i][j] = (f32x4){0.f, 0.f, 0.f, 0.f};

  int frow = lane & 15;
  int fk   = (lane >> 4) << 3;
  int srow = lane >> 3;
  int skk  = (lane & 7) << 3;

  for (int k0 = 0; k0 < K; k0 += 64){
    __syncthreads();
    #pragma unroll
    for (int it = 0; it < 4; ++it){
      int ch  = (wid << 2) | it;
      int row = (ch << 3) | srow;
      __builtin_amdgcn_global_load_lds(
        (const __attribute__((address_space(1))) void*)(A  + (size_t)(m0+row)*K + k0 + skk),
        (__attribute__((address_space(3))) void*)(aT + (ch << 9)), 16, 0, 0);
      __builtin_amdgcn_global_load_lds(
        (const __attribute__((address_space(1))) void*)(BT + (size_t)(n0+row)*K + k0 + skk),
        (__attribute__((address_space(3))) void*)(bT + (ch << 9)), 16, 0, 0);
    }
    __syncthreads();
    #pragma unroll
    for (int kk = 0; kk < 64; kk += 32){
      bf16x8 af[4], bfv[4];
      #pragma unroll
      for (int i = 0; i < 4; ++i)
        af[i]  = *(const bf16x8*)(aT + ((wr*64 + i*16 + frow) << 6) + kk + fk);
      #pragma unroll
      for (int j = 0; j < 4; ++j)
        bfv[j] = *(const bf16x8*)(bT + ((wc*64 + j*16 + frow) << 6) + kk + fk);
      #pragma unroll
      for (int i = 0; i < 4; ++i)
        #pragma unroll
        for (int j = 0; j < 4; ++j)
          acc[i][j] = __builtin_amdgcn_mfma_f32_16x16x32_bf16(af[i], bfv[j], acc[i][j], 0, 0, 0);
    }
  }

  int crow = (lane >> 4) << 2;
  int ccol = lane & 15;
  #pragma unroll
  for (int i = 0; i < 4; ++i)
    #pragma unroll
    for (int j = 0; j < 4; ++j){
      size_t base = (size_t)(m0 + wr*64 + i*16 + crow) * N + (n0 + wc*64 + j*16 + ccol);
      #pragma unroll
      for (int r = 0; r < 4; ++r)
        C[base + (size_t)r * N] = f2bf(acc[i][j][r]);
    }
}

// ---------------- dt = softplus(raw + bias), dA = exp(dt * -exp(A_log)) ----
// writes TRANSPOSED: dtb/dab[(b*32+h)*1024 + t]
__global__ __launch_bounds__(256) void k_dtda(const unsigned short* __restrict__ zx,
                                              const float* __restrict__ dt_bias,
                                              const float* __restrict__ A_log,
                                              float* __restrict__ dtb,
                                              float* __restrict__ dab){
  int i = blockIdx.x*256 + threadIdx.x;
  int r = i >> 5, h = i & 31;
  float raw = bf2f(zx[(size_t)r*NPAD + D_INNER + CONV_DIM + h]) + dt_bias[h];
  float dt  = (raw > 20.f) ? raw : log1pf(expf(raw));
  float A   = -expf(A_log[h]);
  int b = r >> 10, l = r & 1023;
  int o = (b*32 + h)*1024 + l;
  dtb[o] = dt;
  dab[o] = expf(dt * A);
}

// ---------------- causal conv1d (4 taps) + SiLU -------------------
// x channels -> bf16 xbc [r][2048]; B/C channels -> f32 bcf [r][128]
__global__ __launch_bounds__(256) void k_conv(const unsigned short* __restrict__ zx,
                                              const float* __restrict__ conv_w,
                                              const float* __restrict__ conv_b,
                                              unsigned short* __restrict__ xbc,
                                              float* __restrict__ bcf){
  int c = blockIdx.x*256 + threadIdx.x;
  if (c >= CONV_DIM) return;
  int r = blockIdx.y;
  int l = r & (SEQ - 1);
  float v = conv_b[c];
  #pragma unroll
  for (int k = 0; k < 4; ++k){
    int dl = l + k - 3;
    if (dl >= 0)
      v += bf2f(zx[(size_t)(r + k - 3)*NPAD + D_INNER + c]) * conv_w[k*CONV_DIM + c];
  }
  float s = v / (1.f + expf(-v));
  if (c < D_INNER) xbc[(size_t)r*D_INNER + c] = f2bf(s);
  else             bcf[(size_t)r*128 + (c - D_INNER)] = s;
}

// ---------------- scan pass 1: per-chunk local h_end + cumA -----------------
// grid 2048 = bh*8 + c; block 64 (one wave). Barrier-free LDS broadcast.
__global__ __launch_bounds__(64) void k_scan1(const unsigned short* __restrict__ xbc,
                                              const float* __restrict__ bcf,
                                              const float* __restrict__ dtb,
                                              const float* __restrict__ dab,
                                              unsigned short* __restrict__ hend,
                                              float* __restrict__ cumA){
  int id = blockIdx.x;
  int bh = id >> 3, c = id & 7;
  int b  = bh >> 5, h = bh & 31;
  int p  = threadIdx.x;
  __shared__ __align__(16) float Bs[2][64];

#define DH(i) float4 h##i = make_float4(0.f,0.f,0.f,0.f);
  HLIST(DH)
#undef DH
  float ca = 1.f;

  int t0 = c << 7;
  size_t row0 = (size_t)(b*SEQ + t0);
  const float* dtp = dtb + (size_t)bh*1024 + t0;
  const float* dap = dab + (size_t)bh*1024 + t0;

  unsigned short xv = xbc[row0*D_INNER + h*64 + p];
  float bvf = bcf[row0*128 + p];
  float dtv = dtp[0];
  float dAv = dap[0];

  for (int tt = 0; tt < CLEN; ++tt){
    int buf = tt & 1;
    Bs[buf][p] = bvf;
    float xf = bf2f(xv), dtc = dtv, dac = dAv;
    if (tt + 1 < CLEN){
      size_t rn = row0 + tt + 1;
      xv  = xbc[rn*D_INNER + h*64 + p];
      bvf = bcf[rn*128 + p];
      dtv = dtp[tt+1];
      dAv = dap[tt+1];
    }
    float kk = dtc * xf;
    ca *= dac;
#define S1(i) { float4 b4 = *(const float4*)&Bs[buf][(i)<<2]; \
    h##i.x = fmaf(h##i.x, dac, kk*b4.x); \
    h##i.y = fmaf(h##i.y, dac, kk*b4.y); \
    h##i.z = fmaf(h##i.z, dac, kk*b4.z); \
    h##i.w = fmaf(h##i.w, dac, kk*b4.w); }
    HLIST(S1)
#undef S1
  }

  size_t hb = ((size_t)id << 12) + p;
#define ST1(i) \
  hend[hb + (size_t)((i)*4+0)*64] = f2bf(h##i.x); \
  hend[hb + (size_t)((i)*4+1)*64] = f2bf(h##i.y); \
  hend[hb + (size_t)((i)*4+2)*64] = f2bf(h##i.z); \
  hend[hb + (size_t)((i)*4+3)*64] = f2bf(h##i.w);
  HLIST(ST1)
#undef ST1
  if (p == 0) cumA[id] = ca;
}

// ---------------- combine: carry chunk states (in-place hend -> h_init) -----
__global__ __launch_bounds__(256) void k_comb(unsigned short* __restrict__ hh,
                                              const float* __restrict__ cumA){
  int bh = blockIdx.x, tid = threadIdx.x;
  float carry[16];
  #pragma unroll
  for (int i = 0; i < 16; ++i) carry[i] = 0.f;
  #pragma unroll
  for (int c = 0; c < NCHUNK; ++c){
    size_t base = (((size_t)bh*NCHUNK + c) << 12) + tid*16;
    bf16x8 a0 = *(const bf16x8*)(hh + base);
    bf16x8 a1 = *(const bf16x8*)(hh + base + 8);
    float ca = cumA[bh*NCHUNK + c];
    float tmp[16];
    #pragma unroll
    for (int i = 0; i < 8; ++i){
      tmp[i]   = bf2f((unsigned short)a0[i]);
      tmp[8+i] = bf2f((unsigned short)a1[i]);
    }
    bf16x8 w0, w1;
    #pragma unroll
    for (int i = 0; i < 8; ++i){
      w0[i] = (short)f2bf(carry[i]);
      w1[i] = (short)f2bf(carry[8+i]);
    }
    *(bf16x8*)(hh + base)     = w0;
    *(bf16x8*)(hh + base + 8) = w1;
    #pragma unroll
    for (int i = 0; i < 16; ++i) carry[i] = tmp[i] + ca*carry[i];
  }
}

// ---------------- scan pass 2: real scan from h_init, emit y ----------------
__global__ __launch_bounds__(64) void k_scan2(const unsigned short* __restrict__ xbc,
                                              const float* __restrict__ bcf,
                                              const float* __restrict__ dtb,
                                              const float* __restrict__ dab,
                                              const float* __restrict__ Dskip,
                                              const unsigned short* __restrict__ hinit,
                                              unsigned short* __restrict__ y){
  int id = blockIdx.x;
  int bh = id >> 3, c = id & 7;
  int b  = bh >> 5, h = bh & 31;
  int p  = threadIdx.x;
  __shared__ __align__(16) float Bs[2][64];
  __shared__ __align__(16) float Cs[2][64];

  size_t ib = ((size_t)id << 12) + p;
#define LD2(i) float4 h##i; \
  h##i.x = bf2f(hinit[ib + (size_t)((i)*4+0)*64]); \
  h##i.y = bf2f(hinit[ib + (size_t)((i)*4+1)*64]); \
  h##i.z = bf2f(hinit[ib + (size_t)((i)*4+2)*64]); \
  h##i.w = bf2f(hinit[ib + (size_t)((i)*4+3)*64]);
  HLIST(LD2)
#undef LD2
  float dskip_h = Dskip[h];

  int t0 = c << 7;
  size_t row0 = (size_t)(b*SEQ + t0);
  const float* dtp = dtb + (size_t)bh*1024 + t0;
  const float* dap = dab + (size_t)bh*1024 + t0;

  unsigned short xv = xbc[row0*D_INNER + h*64 + p];
  float bvf = bcf[row0*128 + p];
  float cvf = bcf[row0*128 + 64 + p];
  float dtv = dtp[0];
  float dAv = dap[0];

  for (int tt = 0; tt < CLEN; ++tt){
    int buf = tt & 1;
    Bs[buf][p] = bvf;
    Cs[buf][p] = cvf;
    float xf = bf2f(xv), dtc = dtv, dac = dAv;
    if (tt + 1 < CLEN){
      size_t rn = row0 + tt + 1;
      xv  = xbc[rn*D_INNER + h*64 + p];
      bvf = bcf[rn*128 + p];
      cvf = bcf[rn*128 + 64 + p];
      dtv = dtp[tt+1];
      dAv = dap[tt+1];
    }
    float kk = dtc * xf;
    float ys0 = 0.f, ys1 = 0.f, ys2 = 0.f, ys3 = 0.f;
#define S2(i) { float4 b4 = *(const float4*)&Bs[buf][(i)<<2]; \
    float4 c4 = *(const float4*)&Cs[buf][(i)<<2]; \
    h##i.x = fmaf(h##i.x, dac, kk*b4.x); ys0 = fmaf(h##i.x, c4.x, ys0); \
    h##i.y = fmaf(h##i.y, dac, kk*b4.y); ys1 = fmaf(h##i.y, c4.y, ys1); \
    h##i.z = fmaf(h##i.z, dac, kk*b4.z); ys2 = fmaf(h##i.z, c4.z, ys2); \
    h##i.w = fmaf(h##i.w, dac, kk*b4.w); ys3 = fmaf(h##i.w, c4.w, ys3); }
    HLIST(S2)
#undef S2
    float ysum = (ys0 + ys1) + (ys2 + ys3);
    y[(row0 + tt)*D_INNER + h*64 + p] = f2bf(ysum + dskip_h * xf);
  }
}

// ---------------- fused gate + RMS + (norm_w*W_out@head_w) dot --------------
__global__ __launch_bounds__(256) void k_epilogue(const unsigned short* __restrict__ y,
                                                  const unsigned short* __restrict__ zx,
                                                  const float* __restrict__ nwc,
                                                  const float* __restrict__ head_b,
                                                  float* __restrict__ out){
  int r   = blockIdx.x;
  int tid = threadIdx.x;
  bf16x8 y8 = *(const bf16x8*)(y  + (size_t)r*D_INNER + tid*8);
  bf16x8 z8 = *(const bf16x8*)(zx + (size_t)r*NPAD   + tid*8);
  float4 w0 = ((const float4*)nwc)[tid*2];
  float4 w1 = ((const float4*)nwc)[tid*2 + 1];
  float wv[8] = {w0.x, w0.y, w0.z, w0.w, w1.x, w1.y, w1.z, w1.w};
  float s2 = 0.f, sd = 0.f;
  #pragma unroll
  for (int k = 0; k < 8; ++k){
    float yf = bf2f((unsigned short)y8[k]);
    float zf = bf2f((unsigned short)z8[k]);
    float g  = yf * (zf / (1.f + expf(-zf)));
    s2 += g*g; sd += g*wv[k];
  }
  #pragma unroll
  for (int off = 32; off; off >>= 1){
    s2 += __shfl_down(s2, off);
    sd += __shfl_down(sd, off);
  }
  __shared__ float r2[4], rd[4];
  if ((tid & 63) == 0){ r2[tid >> 6] = s2; rd[tid >> 6] = sd; }
  __syncthreads();
  if (tid == 0){
    float t2 = r2[0] + r2[1] + r2[2] + r2[3];
    float td = rd[0] + rd[1] + rd[2] + rd[3];
    out[r] = rsqrtf(t2 * (1.f/2048.f) + 1e-5f) * td + head_b[0];
  }
}

extern "C" void kernel_launch(void* const* d_in, const int* in_sizes, int n_in,
                              void* d_out, int out_size, void* d_ws, size_t ws_size,
                              hipStream_t stream){
  const float* x       = (const float*)d_in[0];
  const float* W_in    = (const float*)d_in[1];
  const float* conv_w  = (const float*)d_in[2];
  const float* conv_b  = (const float*)d_in[3];
  const float* dt_bias = (const float*)d_in[4];
  const float* A_log   = (const float*)d_in[5];
  const float* Dskip   = (const float*)d_in[6];
  const float* norm_w  = (const float*)d_in[7];
  const float* W_out   = (const float*)d_in[8];
  const float* head_w  = (const float*)d_in[9];
  const float* head_b  = (const float*)d_in[10];
  float* out = (float*)d_out;

  // ws layout (peak 168,304,640 B, same as round 3)
  char* ws = (char*)d_ws;
  unsigned short* xb   = (unsigned short*)(ws + 0);            // 16,777,216 (reused: hbuf)
  unsigned short* wt   = (unsigned short*)(ws + 16777216);     //  8,912,896 (reused: bcf+cumA)
  unsigned short* zx16 = (unsigned short*)(ws + 25690112);     // 71,303,168
  unsigned short* xbc  = (unsigned short*)(ws + 96993280);     // 33,554,432 ([r][2048] x only)
  float*          dtb  = (float*)         (ws + 132644864);    //  1,048,576
  float*          dab  = (float*)         (ws + 133693440);    //  1,048,576
  float*          nwc  = (float*)         (ws + 134742016);    //      8,192
  unsigned short* yb   = (unsigned short*)(ws + 134750208);    // 33,554,432

  unsigned short* hbuf = xb;                       // 2048*4096*2B = 16,777,216
  float*          bcf  = (float*)wt;               // 8192*128*4B  =  4,194,304
  float*          cumA = (float*)(ws + 16777216 + 4194304);    // 8,192

  k_convert_x<<<8192, 256, 0, stream>>>(x, xb);
  k_transpose_win<<<dim3(136, 32), 256, 0, stream>>>(W_in, wt);
  k_nwc<<<512, 256, 0, stream>>>(W_out, head_w, norm_w, nwc);
  k_gemm_bf16_bt<<<(NROWS/128)*(NPAD/128), 256, 0, stream>>>(xb, wt, zx16, NROWS, NPAD, D_MODEL);
  k_dtda<<<1024, 256, 0, stream>>>(zx16, dt_bias, A_log, dtb, dab);
  k_conv<<<dim3(9, NROWS), 256, 0, stream>>>(zx16, conv_w, conv_b, xbc, bcf);
  k_scan1<<<256*NCHUNK, 64, 0, stream>>>(xbc, bcf, dtb, dab, hbuf, cumA);
  k_comb<<<256, 256, 0, stream>>>(hbuf, cumA);
  k_scan2<<<256*NCHUNK, 64, 0, stream>>>(xbc, bcf, dtb, dab, Dskip, hbuf, yb);
  k_epilogue<<<NROWS, 256, 0, stream>>>(yb, zx16, nwc, head_b, out);
}

// Round 6
// 329.459 us; speedup vs baseline: 4.4240x; 1.5640x over previous
//
#include <hip/hip_runtime.h>
#include <hip/hip_bf16.h>

#define D_MODEL   1024
#define D_STATE   64
#define D_INNER   2048
#define NHEADS    32
#define CONV_DIM  2176
#define D_IN_PROJ 4256
#define NPAD      4352
#define BATCH     8
#define SEQ       1024
#define NROWS     8192
#define NCHUNK    8
#define CLEN      128

typedef __attribute__((ext_vector_type(8))) short bf16x8;
typedef __attribute__((ext_vector_type(4))) float f32x4;

__device__ __forceinline__ float bf2f(unsigned short u){
  unsigned v = ((unsigned)u) << 16;
  return __builtin_bit_cast(float, v);
}
__device__ __forceinline__ unsigned short f2bf(float f){
  __hip_bfloat16 h = __float2bfloat16(f);
  return __builtin_bit_cast(unsigned short, h);
}

// ---------------- convert x (fp32 -> bf16) ----------------
__global__ __launch_bounds__(256) void k_convert_x(const float* __restrict__ x,
                                                   unsigned short* __restrict__ xb){
  int i = blockIdx.x*256 + threadIdx.x;
  float4 v = ((const float4*)x)[i];
  ushort4 o;
  o.x = f2bf(v.x); o.y = f2bf(v.y); o.z = f2bf(v.z); o.w = f2bf(v.w);
  ((ushort4*)xb)[i] = o;
}

// ---------------- transpose W_in [K][N] -> bf16 [NPAD][K] -------------------
__global__ __launch_bounds__(256) void k_transpose_win(const float* __restrict__ W_in,
                                                       unsigned short* __restrict__ wt){
  __shared__ float tile[32][33];
  int n0 = blockIdx.x * 32;
  int k0 = blockIdx.y * 32;
  int tx = threadIdx.x & 31;
  int ty = threadIdx.x >> 5;
  #pragma unroll
  for (int i = 0; i < 4; ++i){
    int kk = ty + i*8;
    int n  = n0 + tx;
    tile[kk][tx] = (n < D_IN_PROJ) ? W_in[(size_t)(k0+kk)*D_IN_PROJ + n] : 0.f;
  }
  __syncthreads();
  #pragma unroll
  for (int i = 0; i < 4; ++i){
    int nn = ty + i*8;
    wt[(size_t)(n0+nn)*D_MODEL + k0 + tx] = f2bf(tile[tx][nn]);
  }
}

// ---------------- nwc[d] = norm_w[d] * sum_k W_out[d][k]*head_w[k] ----------
__global__ __launch_bounds__(256) void k_nwc(const float* __restrict__ W_out,
                                             const float* __restrict__ head_w,
                                             const float* __restrict__ norm_w,
                                             float* __restrict__ nwc){
  int d    = blockIdx.x*4 + (threadIdx.x >> 6);
  int lane = threadIdx.x & 63;
  const float* row = W_out + (size_t)d * D_MODEL;
  float s = 0.f;
  #pragma unroll
  for (int k = lane; k < D_MODEL; k += 64) s += row[k] * head_w[k];
  #pragma unroll
  for (int off = 32; off; off >>= 1) s += __shfl_down(s, off);
  if (lane == 0) nwc[d] = s * norm_w[d];
}

// ---------------- bf16 MFMA GEMM: C[M][N] = A[M][K] * BT[N][K]^T, bf16 out --
__global__ __launch_bounds__(256) void k_gemm_bf16_bt(const unsigned short* __restrict__ A,
                                                      const unsigned short* __restrict__ BT,
                                                      unsigned short* __restrict__ C,
                                                      int M, int N, int K){
  __shared__ unsigned short aT[128*64];
  __shared__ unsigned short bT[128*64];
  int nb   = N >> 7;
  int m0   = (blockIdx.x / nb) << 7;
  int n0   = (blockIdx.x % nb) << 7;
  int tid  = threadIdx.x;
  int wid  = tid >> 6, lane = tid & 63;
  int wr   = wid >> 1, wc = wid & 1;

  f32x4 acc[4][4];
  #pragma unroll
  for (int i = 0; i < 4; ++i)
    #pragma unroll
    for (int j = 0; j < 4; ++j)
      acc[i][j] = (f32x4){0.f, 0.f, 0.f, 0.f};

  int frow = lane & 15;
  int fk   = (lane >> 4) << 3;
  int srow = lane >> 3;
  int skk  = (lane & 7) << 3;

  for (int k0 = 0; k0 < K; k0 += 64){
    __syncthreads();
    #pragma unroll
    for (int it = 0; it < 4; ++it){
      int ch  = (wid << 2) | it;
      int row = (ch << 3) | srow;
      __builtin_amdgcn_global_load_lds(
        (const __attribute__((address_space(1))) void*)(A  + (size_t)(m0+row)*K + k0 + skk),
        (__attribute__((address_space(3))) void*)(aT + (ch << 9)), 16, 0, 0);
      __builtin_amdgcn_global_load_lds(
        (const __attribute__((address_space(1))) void*)(BT + (size_t)(n0+row)*K + k0 + skk),
        (__attribute__((address_space(3))) void*)(bT + (ch << 9)), 16, 0, 0);
    }
    __syncthreads();
    #pragma unroll
    for (int kk = 0; kk < 64; kk += 32){
      bf16x8 af[4], bfv[4];
      #pragma unroll
      for (int i = 0; i < 4; ++i)
        af[i]  = *(const bf16x8*)(aT + ((wr*64 + i*16 + frow) << 6) + kk + fk);
      #pragma unroll
      for (int j = 0; j < 4; ++j)
        bfv[j] = *(const bf16x8*)(bT + ((wc*64 + j*16 + frow) << 6) + kk + fk);
      #pragma unroll
      for (int i = 0; i < 4; ++i)
        #pragma unroll
        for (int j = 0; j < 4; ++j)
          acc[i][j] = __builtin_amdgcn_mfma_f32_16x16x32_bf16(af[i], bfv[j], acc[i][j], 0, 0, 0);
    }
  }

  int crow = (lane >> 4) << 2;
  int ccol = lane & 15;
  #pragma unroll
  for (int i = 0; i < 4; ++i)
    #pragma unroll
    for (int j = 0; j < 4; ++j){
      size_t base = (size_t)(m0 + wr*64 + i*16 + crow) * N + (n0 + wc*64 + j*16 + ccol);
      #pragma unroll
      for (int r = 0; r < 4; ++r)
        C[base + (size_t)r * N] = f2bf(acc[i][j][r]);
    }
}

// ---------------- dt = softplus(raw + bias), transposed [bh][t] -------------
__global__ __launch_bounds__(256) void k_dtda(const unsigned short* __restrict__ zx,
                                              const float* __restrict__ dt_bias,
                                              float* __restrict__ dtb){
  int i = blockIdx.x*256 + threadIdx.x;
  int r = i >> 5, h = i & 31;
  float raw = bf2f(zx[(size_t)r*NPAD + D_INNER + CONV_DIM + h]) + dt_bias[h];
  float dt  = (raw > 20.f) ? raw : log1pf(expf(raw));
  int b = r >> 10, l = r & 1023;
  dtb[(b*32 + h)*1024 + l] = dt;
}

// ---------------- causal conv1d (4 taps) + SiLU -------------------
// x channels -> bf16 xbc [r][2048]; B/C channels -> bf16 bc16 [r][128]
__global__ __launch_bounds__(256) void k_conv(const unsigned short* __restrict__ zx,
                                              const float* __restrict__ conv_w,
                                              const float* __restrict__ conv_b,
                                              unsigned short* __restrict__ xbc,
                                              unsigned short* __restrict__ bc16){
  int c = blockIdx.x*256 + threadIdx.x;
  if (c >= CONV_DIM) return;
  int r = blockIdx.y;
  int l = r & (SEQ - 1);
  float v = conv_b[c];
  #pragma unroll
  for (int k = 0; k < 4; ++k){
    int dl = l + k - 3;
    if (dl >= 0)
      v += bf2f(zx[(size_t)(r + k - 3)*NPAD + D_INNER + c]) * conv_w[k*CONV_DIM + c];
  }
  float s = v / (1.f + expf(-v));
  if (c < D_INNER) xbc[(size_t)r*D_INNER + c] = f2bf(s);
  else             bc16[(size_t)r*128 + (c - D_INNER)] = f2bf(s);
}

// ---------------- per-chunk inclusive cumsum of dt + cumA -------------------
__global__ __launch_bounds__(64) void k_cs(const float* __restrict__ dtb,
                                           const float* __restrict__ A_log,
                                           float* __restrict__ csb,
                                           float* __restrict__ cumA){
  int id = blockIdx.x;                 // bh*8 + c
  int bh = id >> 3, c = id & 7;
  int h  = bh & 31;
  int l  = threadIdx.x;
  const float* src = dtb + (size_t)bh*1024 + (c << 7);
  float d0 = src[2*l], d1 = src[2*l + 1];
  float pr = d0 + d1;
  float s  = pr;
  #pragma unroll
  for (int off = 1; off < 64; off <<= 1){
    float n = __shfl_up(s, off);
    if (l >= off) s += n;
  }
  float excl = s - pr;
  csb[(size_t)id*128 + 2*l]     = excl + d0;
  csb[(size_t)id*128 + 2*l + 1] = excl + pr;
  if (l == 63){
    float A = -expf(A_log[h]);
    cumA[id] = expf(A * s);
  }
}

// ---------------- SSD pass 1: h_end_local[p][s] = (w*X)^T @ B ---------------
// grid 2048 (bh*8+c), block 256 (4 waves). w[tau] = dt*exp(A*(csT-cs[tau])).
__global__ __launch_bounds__(256) void k_ssd1(const unsigned short* __restrict__ xbc,
                                              const unsigned short* __restrict__ bc16,
                                              const float* __restrict__ dtb,
                                              const float* __restrict__ csb,
                                              const float* __restrict__ A_log,
                                              unsigned short* __restrict__ hend){
  __shared__ __align__(16) unsigned short XTw[64*136];
  __shared__ __align__(16) unsigned short BTl[64*136];
  int id = blockIdx.x;
  int bh = id >> 3, c = id & 7;
  int b  = bh >> 5, h = bh & 31;
  int tid = threadIdx.x;
  int w = tid >> 6, l = tid & 63;
  float A = -expf(A_log[h]);
  int row0 = b*SEQ + (c << 7);
  float csT = csb[(size_t)id*128 + 127];

  #pragma unroll
  for (int it = 0; it < 4; ++it){
    int idx = it*256 + tid;
    int tau = idx >> 3, pb = idx & 7;
    bf16x8 v = *(const bf16x8*)(xbc + (size_t)(row0+tau)*D_INNER + h*64 + pb*8);
    float wgt = dtb[(size_t)bh*1024 + (c<<7) + tau]
              * expf(A*(csT - csb[(size_t)id*128 + tau]));
    #pragma unroll
    for (int j = 0; j < 8; ++j)
      XTw[(pb*8+j)*136 + tau] = f2bf(bf2f((unsigned short)v[j]) * wgt);
  }
  #pragma unroll
  for (int it = 0; it < 4; ++it){
    int idx = it*256 + tid;
    int tau = idx >> 3, sb = idx & 7;
    bf16x8 v = *(const bf16x8*)(bc16 + (size_t)(row0+tau)*128 + sb*8);
    #pragma unroll
    for (int j = 0; j < 8; ++j)
      BTl[(sb*8+j)*136 + tau] = (unsigned short)v[j];
  }
  __syncthreads();

  int fr = l & 15, fo = (l >> 4) << 3;
  f32x4 acc[4];
  #pragma unroll
  for (int n = 0; n < 4; ++n) acc[n] = (f32x4){0.f,0.f,0.f,0.f};
  #pragma unroll
  for (int kt = 0; kt < 4; ++kt){
    bf16x8 pf = *(const bf16x8*)(XTw + (w*16+fr)*136 + kt*32 + fo);
    #pragma unroll
    for (int n = 0; n < 4; ++n){
      bf16x8 qf = *(const bf16x8*)(BTl + (n*16+fr)*136 + kt*32 + fo);
      acc[n] = __builtin_amdgcn_mfma_f32_16x16x32_bf16(pf, qf, acc[n], 0, 0, 0);
    }
  }
  #pragma unroll
  for (int n = 0; n < 4; ++n)
    #pragma unroll
    for (int r = 0; r < 4; ++r){
      int p = w*16 + ((l>>4)<<2) + r;
      int s = n*16 + fr;
      hend[(size_t)id*4096 + p*64 + s] = f2bf(acc[n][r]);
    }
}

// ---------------- combine: carry chunk states (in-place hend -> h_init) -----
__global__ __launch_bounds__(256) void k_comb(unsigned short* __restrict__ hh,
                                              const float* __restrict__ cumA){
  int bh = blockIdx.x, tid = threadIdx.x;
  float carry[16];
  #pragma unroll
  for (int i = 0; i < 16; ++i) carry[i] = 0.f;
  #pragma unroll
  for (int c = 0; c < NCHUNK; ++c){
    size_t base = (((size_t)bh*NCHUNK + c) << 12) + tid*16;
    bf16x8 a0 = *(const bf16x8*)(hh + base);
    bf16x8 a1 = *(const bf16x8*)(hh + base + 8);
    float ca = cumA[bh*NCHUNK + c];
    float tmp[16];
    #pragma unroll
    for (int i = 0; i < 8; ++i){
      tmp[i]   = bf2f((unsigned short)a0[i]);
      tmp[8+i] = bf2f((unsigned short)a1[i]);
    }
    bf16x8 w0, w1;
    #pragma unroll
    for (int i = 0; i < 8; ++i){
      w0[i] = (short)f2bf(carry[i]);
      w1[i] = (short)f2bf(carry[8+i]);
    }
    *(bf16x8*)(hh + base)     = w0;
    *(bf16x8*)(hh + base + 8) = w1;
    #pragma unroll
    for (int i = 0; i < 16; ++i) carry[i] = tmp[i] + ca*carry[i];
  }
}

// ---------------- SSD pass 2: Y = (mask.(C B^T)) X + diag(a) (C h_init) -----
// grid 2048 (bh*8+c), block 256 (4 waves). Wave w owns m-tiles {w, 7-w}.
// G in a DEDICATED LDS buffer (no overlay of live staging regions).
__global__ __launch_bounds__(256) void k_ssd2(const unsigned short* __restrict__ xbc,
                                              const unsigned short* __restrict__ bc16,
                                              const float* __restrict__ dtb,
                                              const float* __restrict__ csb,
                                              const float* __restrict__ A_log,
                                              const float* __restrict__ Dskip,
                                              const unsigned short* __restrict__ hbuf,
                                              unsigned short* __restrict__ yb){
  __shared__ __align__(16) unsigned short Bl[128*72];
  __shared__ __align__(16) unsigned short Cl[128*72];
  __shared__ __align__(16) unsigned short XTl[64*136];
  __shared__ __align__(16) unsigned short hl[64*72];
  __shared__ __align__(16) unsigned short Gm[128*136];
  __shared__ float cs_l[128], dt_l[128], a_l[128];

  int id = blockIdx.x;
  int bh = id >> 3, c = id & 7;
  int b  = bh >> 5, h = bh & 31;
  int tid = threadIdx.x;
  int w = tid >> 6, l = tid & 63;
  float A = -expf(A_log[h]);
  int row0 = b*SEQ + (c << 7);

  // stage B and C
  #pragma unroll
  for (int it = 0; it < 8; ++it){
    int idx = it*256 + tid;
    int tau = idx >> 4, cb = idx & 15;
    bf16x8 v = *(const bf16x8*)(bc16 + (size_t)(row0+tau)*128 + cb*8);
    unsigned short* dst = (cb < 8) ? (Bl + tau*72 + cb*8)
                                   : (Cl + tau*72 + (cb-8)*8);
    *(bf16x8*)dst = v;
  }
  // stage X^T
  #pragma unroll
  for (int it = 0; it < 4; ++it){
    int idx = it*256 + tid;
    int tau = idx >> 3, pb = idx & 7;
    bf16x8 v = *(const bf16x8*)(xbc + (size_t)(row0+tau)*D_INNER + h*64 + pb*8);
    #pragma unroll
    for (int j = 0; j < 8; ++j)
      XTl[(pb*8+j)*136 + tau] = (unsigned short)v[j];
  }
  // stage h_init [p][s]
  #pragma unroll
  for (int it = 0; it < 2; ++it){
    int idx = it*256 + tid;
    int p = idx >> 3, sb = idx & 7;
    bf16x8 v = *(const bf16x8*)(hbuf + (size_t)id*4096 + p*64 + sb*8);
    *(bf16x8*)(hl + p*72 + sb*8) = v;
  }
  if (tid < 128){
    float cs = csb[(size_t)id*128 + tid];
    cs_l[tid] = cs;
    dt_l[tid] = dtb[(size_t)bh*1024 + (c<<7) + tid];
    a_l[tid]  = expf(A*cs);
  }
  __syncthreads();

  int fr = l & 15, fo = (l >> 4) << 3;
  int mtB = 7 - w;

  // Step A: Y = C·h_init, then scale rows by a[t]
  f32x4 Y[2][4];
  #pragma unroll
  for (int mi = 0; mi < 2; ++mi)
    #pragma unroll
    for (int n = 0; n < 4; ++n) Y[mi][n] = (f32x4){0.f,0.f,0.f,0.f};
  #pragma unroll
  for (int mi = 0; mi < 2; ++mi){
    int mt = mi ? mtB : w;
    #pragma unroll
    for (int kt = 0; kt < 2; ++kt){
      bf16x8 pf = *(const bf16x8*)(Cl + (mt*16+fr)*72 + kt*32 + fo);
      #pragma unroll
      for (int n = 0; n < 4; ++n){
        bf16x8 qf = *(const bf16x8*)(hl + (n*16+fr)*72 + kt*32 + fo);
        Y[mi][n] = __builtin_amdgcn_mfma_f32_16x16x32_bf16(pf, qf, Y[mi][n], 0, 0, 0);
      }
    }
    #pragma unroll
    for (int r = 0; r < 4; ++r){
      float av = a_l[mt*16 + ((l>>4)<<2) + r];
      #pragma unroll
      for (int n = 0; n < 4; ++n) Y[mi][n][r] *= av;
    }
  }

  // Step B: S = C·B^T on lower-triangular tiles; mask+scale in regs
  f32x4 Sv[9];
  #pragma unroll
  for (int slot = 0; slot < 9; ++slot){
    int mt = (slot <= w) ? w : mtB;
    int nt = (slot <= w) ? slot : slot - w - 1;
    f32x4 acc = (f32x4){0.f,0.f,0.f,0.f};
    #pragma unroll
    for (int kt = 0; kt < 2; ++kt){
      bf16x8 pf = *(const bf16x8*)(Cl + (mt*16+fr)*72 + kt*32 + fo);
      bf16x8 qf = *(const bf16x8*)(Bl + (nt*16+fr)*72 + kt*32 + fo);
      acc = __builtin_amdgcn_mfma_f32_16x16x32_bf16(pf, qf, acc, 0, 0, 0);
    }
    int tau = nt*16 + fr;
    float dtt = dt_l[tau];
    float cst = cs_l[tau];
    #pragma unroll
    for (int r = 0; r < 4; ++r){
      int t = mt*16 + ((l>>4)<<2) + r;
      float v = acc[r] * dtt * expf(A*(cs_l[t] - cst));
      acc[r] = (tau <= t) ? v : 0.f;
    }
    Sv[slot] = acc;
  }

  __syncthreads();

  #pragma unroll
  for (int slot = 0; slot < 9; ++slot){
    int mt = (slot <= w) ? w : mtB;
    int nt = (slot <= w) ? slot : slot - w - 1;
    int tau = nt*16 + fr;
    #pragma unroll
    for (int r = 0; r < 4; ++r){
      int t = mt*16 + ((l>>4)<<2) + r;
      Gm[t*136 + tau] = f2bf(Sv[slot][r]);
    }
  }
  { // zero-fill the diagonal-adjacent tile of the even m-tile (k rounds to 32)
    int mtE = (w & 1) ? mtB : w;
    int ntE = mtE + 1;
    #pragma unroll
    for (int r = 0; r < 4; ++r){
      int t = mtE*16 + ((l>>4)<<2) + r;
      Gm[t*136 + ntE*16 + fr] = 0;
    }
  }
  __syncthreads();

  // Step C: Y += G·X (k only up to diagonal)
  #pragma unroll
  for (int mi = 0; mi < 2; ++mi){
    int mt = mi ? mtB : w;
    int kmax = (mt + 2) >> 1;
    for (int kt2 = 0; kt2 < kmax; ++kt2){
      bf16x8 pf = *(const bf16x8*)(Gm + (mt*16+fr)*136 + kt2*32 + fo);
      #pragma unroll
      for (int n = 0; n < 4; ++n){
        bf16x8 qf = *(const bf16x8*)(XTl + (n*16+fr)*136 + kt2*32 + fo);
        Y[mi][n] = __builtin_amdgcn_mfma_f32_16x16x32_bf16(pf, qf, Y[mi][n], 0, 0, 0);
      }
    }
  }

  // output: y = Y + Dskip * x
  float dsk = Dskip[h];
  #pragma unroll
  for (int mi = 0; mi < 2; ++mi){
    int mt = mi ? mtB : w;
    #pragma unroll
    for (int r = 0; r < 4; ++r){
      int t = mt*16 + ((l>>4)<<2) + r;
      size_t orow = (size_t)(row0 + t)*D_INNER + h*64;
      #pragma unroll
      for (int n = 0; n < 4; ++n){
        int p = n*16 + fr;
        float xv = bf2f(XTl[p*136 + t]);
        yb[orow + p] = f2bf(Y[mi][n][r] + dsk*xv);
      }
    }
  }
}

// ---------------- fused gate + RMS + (norm_w*W_out@head_w) dot --------------
__global__ __launch_bounds__(256) void k_epilogue(const unsigned short* __restrict__ y,
                                                  const unsigned short* __restrict__ zx,
                                                  const float* __restrict__ nwc,
                                                  const float* __restrict__ head_b,
                                                  float* __restrict__ out){
  int r   = blockIdx.x;
  int tid = threadIdx.x;
  bf16x8 y8 = *(const bf16x8*)(y  + (size_t)r*D_INNER + tid*8);
  bf16x8 z8 = *(const bf16x8*)(zx + (size_t)r*NPAD   + tid*8);
  float4 w0 = ((const float4*)nwc)[tid*2];
  float4 w1 = ((const float4*)nwc)[tid*2 + 1];
  float wv[8] = {w0.x, w0.y, w0.z, w0.w, w1.x, w1.y, w1.z, w1.w};
  float s2 = 0.f, sd = 0.f;
  #pragma unroll
  for (int k = 0; k < 8; ++k){
    float yf = bf2f((unsigned short)y8[k]);
    float zf = bf2f((unsigned short)z8[k]);
    float g  = yf * (zf / (1.f + expf(-zf)));
    s2 += g*g; sd += g*wv[k];
  }
  #pragma unroll
  for (int off = 32; off; off >>= 1){
    s2 += __shfl_down(s2, off);
    sd += __shfl_down(sd, off);
  }
  __shared__ float r2[4], rd[4];
  if ((tid & 63) == 0){ r2[tid >> 6] = s2; rd[tid >> 6] = sd; }
  __syncthreads();
  if (tid == 0){
    float t2 = r2[0] + r2[1] + r2[2] + r2[3];
    float td = rd[0] + rd[1] + rd[2] + rd[3];
    out[r] = rsqrtf(t2 * (1.f/2048.f) + 1e-5f) * td + head_b[0];
  }
}

extern "C" void kernel_launch(void* const* d_in, const int* in_sizes, int n_in,
                              void* d_out, int out_size, void* d_ws, size_t ws_size,
                              hipStream_t stream){
  const float* x       = (const float*)d_in[0];
  const float* W_in    = (const float*)d_in[1];
  const float* conv_w  = (const float*)d_in[2];
  const float* conv_b  = (const float*)d_in[3];
  const float* dt_bias = (const float*)d_in[4];
  const float* A_log   = (const float*)d_in[5];
  const float* Dskip   = (const float*)d_in[6];
  const float* norm_w  = (const float*)d_in[7];
  const float* W_out   = (const float*)d_in[8];
  const float* head_w  = (const float*)d_in[9];
  const float* head_b  = (const float*)d_in[10];
  float* out = (float*)d_out;

  char* ws = (char*)d_ws;
  unsigned short* xb   = (unsigned short*)(ws + 0);            // 16,777,216 (reused: hbuf)
  unsigned short* wt   = (unsigned short*)(ws + 16777216);     //  8,912,896 W_in^T (reused: bc16|csb|cumA)
  unsigned short* zx16 = (unsigned short*)(ws + 25690112);     // 71,303,168
  unsigned short* xbc  = (unsigned short*)(ws + 96993280);     // 33,554,432 ([r][2048] x only)
  float*          dtb  = (float*)         (ws + 132644864);    //  1,048,576
  float*          nwc  = (float*)         (ws + 134742016);    //      8,192
  unsigned short* yb   = (unsigned short*)(ws + 134750208);    // 33,554,432

  unsigned short* hbuf = xb;                                   // 2048*4096*2B
  unsigned short* bc16 = wt;                                   // 8192*128*2B = 2,097,152
  float*          csb  = (float*)(ws + 16777216 + 2097152);    // 2048*128*4B = 1,048,576
  float*          cumA = (float*)(ws + 16777216 + 3145728);    // 8,192

  k_convert_x<<<8192, 256, 0, stream>>>(x, xb);
  k_transpose_win<<<dim3(136, 32), 256, 0, stream>>>(W_in, wt);
  k_nwc<<<512, 256, 0, stream>>>(W_out, head_w, norm_w, nwc);
  k_gemm_bf16_bt<<<(NROWS/128)*(NPAD/128), 256, 0, stream>>>(xb, wt, zx16, NROWS, NPAD, D_MODEL);
  k_dtda<<<1024, 256, 0, stream>>>(zx16, dt_bias, dtb);
  k_conv<<<dim3(9, NROWS), 256, 0, stream>>>(zx16, conv_w, conv_b, xbc, bc16);
  k_cs<<<2048, 64, 0, stream>>>(dtb, A_log, csb, cumA);
  k_ssd1<<<2048, 256, 0, stream>>>(xbc, bc16, dtb, csb, A_log, hbuf);
  k_comb<<<256, 256, 0, stream>>>(hbuf, cumA);
  k_ssd2<<<2048, 256, 0, stream>>>(xbc, bc16, dtb, csb, A_log, Dskip, hbuf, yb);
  k_epilogue<<<NROWS, 256, 0, stream>>>(yb, zx16, nwc, head_b, out);
}